// Round 8
// baseline (119.644 us; speedup 1.0000x reference)
//
#include <hip/hip_runtime.h>

// Depthwise Gaussian blur K=121, replicate pad, separable, fp32. FUSED.
// R8: span-interleaved LDS layout q[i]=(v[i],v[i+256]) as float2, groups of
// 4 float2 (8 floats) + 2 pad -> lane b128 bases 20L mod 32 tile all 32
// banks perfectly (R7 had 7.9M conflict cyc). H pass = float2 sliding
// window (packs for v_pk_fma_f32, halves window regs). Halo via __shfl
// pre-barrier (2 barriers total). Butterfly make_weights (3 exps).

#define HH    512
#define WW    512
#define PLANE (512 * 512)
#define NIMG  24
#define SROW  960     // floats per LDS row: 96 groups * (8 real + 2 pad)

__device__ __forceinline__ int qla(int s) {      // float offset of q[s].x
    return 10 * (s >> 2) + 2 * (s & 3);
}

// wave-butterfly weight build: ~3 __expf + 6 shfl per thread
__device__ __forceinline__ void make_weights(const float* __restrict__ sigma,
                                             float* __restrict__ wlds, int tid) {
    const float s = sigma[0] * 8.0f + 16.0f;
    const float inv2v = 1.0f / (2.0f * s * s);
    const int lane = tid & 63;
    const float c1 = (float)lane - 60.0f;
    float sum = __expf(-c1 * c1 * inv2v);        // taps 0..63
    if (lane + 64 <= 120) {                      // taps 64..120
        const float c2 = (float)(lane + 64) - 60.0f;
        sum += __expf(-c2 * c2 * inv2v);
    }
    #pragma unroll
    for (int off = 1; off < 64; off <<= 1) sum += __shfl_xor(sum, off);
    if (tid < 128) {
        float g = 0.0f;
        if (tid <= 120) {
            const float c = (float)tid - 60.0f;
            g = __expf(-c * c * inv2v);
        }
        wlds[tid] = g / sum;                     // taps 121..127 exactly 0
    }
}

// ---- vertical octet: global-streamed float2 window (as R7) ------------------
#define V_OCT(CUR, NXT, KO)                                               \
    { *(float4*)&wq[0] = *(const float4*)&wlds[(KO) * 8];                 \
      *(float4*)&wq[4] = *(const float4*)&wlds[(KO) * 8 + 4];             \
      _Pragma("unroll")                                                   \
      for (int ki = 0; ki < 8; ++ki) {                                    \
          int rr = r0 - 52 + (KO) * 8 + ki;                               \
          rr = rr < 0 ? 0 : (rr > HH - 1 ? HH - 1 : rr);                  \
          NXT[ki] = *(const float2*)&src[(size_t)rr * WW];                \
          const float wk = wq[ki];                                        \
          _Pragma("unroll")                                               \
          for (int j = 0; j < 8; ++j) {                                   \
              const int idx = ki + j;                                     \
              const float2 v = (idx < 8) ? CUR[idx] : NXT[idx - 8];       \
              vac[j].x += wk * v.x; vac[j].y += wk * v.y;                 \
          }                                                               \
      }                                                                   \
    }

// ---- horizontal: load window block MB (8 float2 = 4 b128, perfect tiling) --
#define LOADW(DST, MB)                                                    \
    { const int F = 20 * (L + (MB));                                      \
      const float4 A = *(const float4*)&bs[F];                            \
      const float4 Bq = *(const float4*)&bs[F + 4];                       \
      const float4 Cq = *(const float4*)&bs[F + 10];                      \
      const float4 Dq = *(const float4*)&bs[F + 14];                      \
      DST[0] = make_float2(A.x, A.y);   DST[1] = make_float2(A.z, A.w);   \
      DST[2] = make_float2(Bq.x, Bq.y); DST[3] = make_float2(Bq.z, Bq.w); \
      DST[4] = make_float2(Cq.x, Cq.y); DST[5] = make_float2(Cq.z, Cq.w); \
      DST[6] = make_float2(Dq.x, Dq.y); DST[7] = make_float2(Dq.z, Dq.w); }

#define H_OCT(CUR, NXT, KO)                                               \
    { LOADW(NXT, (KO) + 1)                                                \
      *(float4*)&wq[0] = *(const float4*)&wlds[(KO) * 8];                 \
      *(float4*)&wq[4] = *(const float4*)&wlds[(KO) * 8 + 4];             \
      _Pragma("unroll")                                                   \
      for (int ki = 0; ki < 8; ++ki) {                                    \
          const float wk = wq[ki];                                        \
          _Pragma("unroll")                                               \
          for (int j = 0; j < 8; ++j) {                                   \
              const int idx = ki + j;                                     \
              const float2 v = (idx < 8) ? CUR[idx] : NXT[idx - 8];       \
              hac[j].x += wk * v.x; hac[j].y += wk * v.y;                 \
          }                                                               \
      }                                                                   \
    }

__global__ __launch_bounds__(256, 5) void blur_fused(
        const float* __restrict__ x, const float* __restrict__ sigma,
        float* __restrict__ out) {
    __shared__ float sm[8 * SROW];               // 30 KB -> 5 blocks/CU
    __shared__ float wlds[128];
    const int tid = threadIdx.x;

    // XCD swizzle: contiguous 192-tile span per XCD (keeps windows in-L2)
    const int lid   = blockIdx.x + gridDim.x * blockIdx.y;   // 0..1535
    const int tile  = (lid & 7) * 192 + (lid >> 3);
    const int r0    = (tile & 63) * 8;           // output rows r0..r0+7
    const int plane = tile >> 6;

    const int c0 = tid * 2;                      // this thread's cols c0,c0+1
    const float* __restrict__ src = x + (size_t)plane * PLANE + c0;

    // ---- vertical: 8 rows x 2 cols, global-streamed window ---------------
    float2 wa[8], wb[8], vac[8];
    float  wq[8];
    #pragma unroll
    for (int m = 0; m < 8; ++m) {                // rows r0-60..r0-53
        int rr = r0 - 60 + m;
        rr = rr < 0 ? 0 : rr;
        wa[m] = *(const float2*)&src[(size_t)rr * WW];
    }
    make_weights(sigma, wlds, tid);
    #pragma unroll
    for (int j = 0; j < 8; ++j) vac[j] = make_float2(0.f, 0.f);
    __syncthreads();                             // wlds ready

    #pragma unroll 1
    for (int ko = 0; ko < 16; ko += 2) {
        V_OCT(wa, wb, ko)
        V_OCT(wb, wa, ko + 1)
    }

    // ---- scatter into span-interleaved q[]: q[s]=(v[s-60], v[s+196]) -----
    {
        const int laX0 = qla(c0 + 60), laX1 = qla(c0 + 61);
        const int laY0 = qla(c0 - 196) + 1, laY1 = qla(c0 - 195) + 1;
        #pragma unroll
        for (int j = 0; j < 8; ++j) {
            float* rp = sm + j * SROW;
            if (c0 < 324) { rp[laX0] = vac[j].x; rp[laX1] = vac[j].y; }
            if (c0 >= 196) { rp[laY0] = vac[j].x; rp[laY1] = vac[j].y; }
        }
    }
    // ---- replicate halo via shfl (no extra barrier) ----------------------
    if (tid < 64) {                              // left: q[s<60].x = v[0]
        #pragma unroll
        for (int j = 0; j < 8; ++j) {
            const float lv = __shfl(vac[j].x, 0);
            if (tid < 60) sm[j * SROW + qla(tid)] = lv;
        }
    } else if (tid >= 192) {                     // right: q[s>=316].y = v[511]
        const int l = tid & 63;
        #pragma unroll
        for (int j = 0; j < 8; ++j) {
            const float rv = __shfl(vac[j].y, 63);
            sm[j * SROW + qla(316 + l) + 1] = rv;
            if (l < 4) sm[j * SROW + qla(380 + l) + 1] = rv;
        }
    }
    __syncthreads();

    // ---- horizontal: float2 window, 8 output-pairs per lane --------------
    const int r = tid >> 5;                      // 0..7
    const int L = tid & 31;                      // pair-cols (8L+j, 8L+256+j)
    const float* __restrict__ bs = sm + r * SROW;

    float2 ha[8], hb[8], hac[8];
    #pragma unroll
    for (int j = 0; j < 8; ++j) hac[j] = make_float2(0.f, 0.f);

    LOADW(ha, 0)

    #pragma unroll 1
    for (int ko = 0; ko < 16; ko += 2) {
        H_OCT(ha, hb, ko)
        H_OCT(hb, ha, ko + 1)
    }

    float* __restrict__ dst = out + (size_t)plane * PLANE
                                  + (size_t)(r0 + r) * WW + L * 8;
    *(float4*)(dst)       = make_float4(hac[0].x, hac[1].x, hac[2].x, hac[3].x);
    *(float4*)(dst + 4)   = make_float4(hac[4].x, hac[5].x, hac[6].x, hac[7].x);
    *(float4*)(dst + 256) = make_float4(hac[0].y, hac[1].y, hac[2].y, hac[3].y);
    *(float4*)(dst + 260) = make_float4(hac[4].y, hac[5].y, hac[6].y, hac[7].y);
}

extern "C" void kernel_launch(void* const* d_in, const int* in_sizes, int n_in,
                              void* d_out, int out_size, void* d_ws, size_t ws_size,
                              hipStream_t stream) {
    const float* x     = (const float*)d_in[0];
    const float* sigma = (const float*)d_in[1];
    float* out = (float*)d_out;
    blur_fused<<<dim3(HH / 8, NIMG), dim3(256), 0, stream>>>(x, sigma, out);
}